// Round 1
// baseline (426.990 us; speedup 1.0000x reference)
//
#include <hip/hip_runtime.h>

// TriPlane sampling: out[n, 0:32] = coarse(xy)+coarse(xz)+coarse(yz),
//                    out[n,32:64] = fine(xy)+fine(xz)+fine(yz)
// Planes arrive [C=32, H, W]; we transpose to [H, W, C] in d_ws so each
// bilinear corner's 32 channels are one contiguous 128B segment.

#define CDIM 32

// ---- transpose [32, HW] -> [HW, 32], LDS-tiled, 64 positions per block ----
__global__ void transpose_plane(const float* __restrict__ in,
                                float* __restrict__ out, int HW) {
    __shared__ float lds[64][33];  // +1 pad: no bank conflicts
    int p0  = blockIdx.x * 64;
    int tid = threadIdx.x;         // 256 threads = 4 waves
    int pi  = tid & 63;
    int cg  = tid >> 6;            // 0..3
#pragma unroll
    for (int i = 0; i < 8; ++i) {
        int c = cg * 8 + i;        // 0..31
        int p = p0 + pi;
        float v = (p < HW) ? in[(size_t)c * HW + p] : 0.0f;  // coalesced read
        lds[pi][c] = v;
    }
    __syncthreads();
    int c2 = tid & 31;
    int pj = tid >> 5;             // 0..7
#pragma unroll
    for (int i = 0; i < 8; ++i) {
        int p = pj + i * 8;        // 0..63
        if (p0 + p < HW)
            out[(size_t)(p0 + p) * CDIM + c2] = lds[p][c2];  // coalesced write
    }
}

// ---- bilinear fetch of 4 channels from a channel-last [R,R,32] plane ----
__device__ __forceinline__ float4 bilerp4(const float* __restrict__ base,
                                          int R, float u, float v, int c4) {
    float s = 0.5f * (float)(R - 1);
    float x = (u + 1.0f) * s;
    float y = (v + 1.0f) * s;
    float rm1 = (float)(R - 1);
    x = fminf(fmaxf(x, 0.0f), rm1);
    y = fminf(fmaxf(y, 0.0f), rm1);
    float x0f = floorf(x), y0f = floorf(y);
    int x0 = (int)x0f, y0 = (int)y0f;
    int x1 = min(x0 + 1, R - 1);
    int y1 = min(y0 + 1, R - 1);
    float wx = x - x0f, wy = y - y0f;

    const float* r0 = base + ((size_t)y0 * R) * CDIM + c4;
    const float* r1 = base + ((size_t)y1 * R) * CDIM + c4;
    float4 a = *(const float4*)(r0 + (size_t)x0 * CDIM);
    float4 b = *(const float4*)(r0 + (size_t)x1 * CDIM);
    float4 c = *(const float4*)(r1 + (size_t)x0 * CDIM);
    float4 d = *(const float4*)(r1 + (size_t)x1 * CDIM);

    float w00 = (1.0f - wx) * (1.0f - wy);
    float w01 = wx * (1.0f - wy);
    float w10 = (1.0f - wx) * wy;
    float w11 = wx * wy;
    float4 r;
    r.x = a.x * w00 + b.x * w01 + c.x * w10 + d.x * w11;
    r.y = a.y * w00 + b.y * w01 + c.y * w10 + d.y * w11;
    r.z = a.z * w00 + b.z * w01 + c.z * w10 + d.z * w11;
    r.w = a.w * w00 + b.w * w01 + c.w * w10 + d.w * w11;
    return r;
}

// ---- main sampler: 16 threads per point (2 levels x 8 channel-quads) ----
__global__ void triplane_sample(const float* __restrict__ xyz,
                                const float* __restrict__ planes,
                                float* __restrict__ out, int n_pts) {
    int tid = blockIdx.x * blockDim.x + threadIdx.x;
    int n = tid >> 4;
    if (n >= n_pts) return;
    int l     = tid & 15;
    int level = l >> 3;        // 0 = coarse, 1 = fine
    int c4    = (l & 7) * 4;   // channel quad

    float px = xyz[3 * (size_t)n + 0];
    float py = xyz[3 * (size_t)n + 1];
    float pz = xyz[3 * (size_t)n + 2];
    // g = (p - (-4)) * 2/8 - 1  (same arithmetic as reference)
    float gx = (px + 4.0f) * 0.25f - 1.0f;
    float gy = (py + 4.0f) * 0.25f - 1.0f;
    float gz = (pz + 4.0f) * 0.25f - 1.0f;

    const size_t CSZ = (size_t)100 * 100 * CDIM;  // 320000
    const size_t FSZ = (size_t)400 * 400 * CDIM;  // 5120000
    const float* base;
    int R;
    size_t psz;
    if (level == 0) { base = planes;           R = 100; psz = CSZ; }
    else            { base = planes + 3 * CSZ; R = 400; psz = FSZ; }

    float4 fxy = bilerp4(base,           R, gx, gy, c4);
    float4 fxz = bilerp4(base + psz,     R, gx, gz, c4);
    float4 fyz = bilerp4(base + 2 * psz, R, gy, gz, c4);

    float4 r;
    r.x = fxy.x + fxz.x + fyz.x;
    r.y = fxy.y + fxz.y + fyz.y;
    r.z = fxy.z + fxz.z + fyz.z;
    r.w = fxy.w + fxz.w + fyz.w;

    // out[n, level*32 + c4 .. +3]  -> fully coalesced float4 store
    *(float4*)(out + (size_t)n * 64 + level * 32 + c4) = r;
}

extern "C" void kernel_launch(void* const* d_in, const int* in_sizes, int n_in,
                              void* d_out, int out_size, void* d_ws, size_t ws_size,
                              hipStream_t stream) {
    const float* xyz = (const float*)d_in[0];
    float* ws = (float*)d_ws;
    int n = in_sizes[0] / 3;

    const int CHW = 100 * 100;
    const int FHW = 400 * 400;
    const size_t CSZ = (size_t)CHW * CDIM;
    const size_t FSZ = (size_t)FHW * CDIM;

    dim3 blk(256);
    // coarse planes -> ws[0 .. 3*CSZ)
    transpose_plane<<<(CHW + 63) / 64, blk, 0, stream>>>((const float*)d_in[1], ws, CHW);
    transpose_plane<<<(CHW + 63) / 64, blk, 0, stream>>>((const float*)d_in[2], ws + CSZ, CHW);
    transpose_plane<<<(CHW + 63) / 64, blk, 0, stream>>>((const float*)d_in[3], ws + 2 * CSZ, CHW);
    // fine planes -> ws[3*CSZ .. 3*CSZ + 3*FSZ)
    transpose_plane<<<(FHW + 63) / 64, blk, 0, stream>>>((const float*)d_in[4], ws + 3 * CSZ, FHW);
    transpose_plane<<<(FHW + 63) / 64, blk, 0, stream>>>((const float*)d_in[5], ws + 3 * CSZ + FSZ, FHW);
    transpose_plane<<<(FHW + 63) / 64, blk, 0, stream>>>((const float*)d_in[6], ws + 3 * CSZ + 2 * FSZ, FHW);

    long long total_threads = (long long)n * 16;
    int nblk = (int)((total_threads + 255) / 256);
    triplane_sample<<<nblk, blk, 0, stream>>>(xyz, ws, (float*)d_out, n);
}

// Round 2
// 323.209 us; speedup vs baseline: 1.3211x; 1.3211x over previous
//
#include <hip/hip_runtime.h>

// TriPlane sampling with spatial counting-sort.
// Pipeline: (1) transpose 6 planes [C,H,W] -> [H,W,C] in d_ws
//           (2) counting-sort points into 32^3 cells (hist -> scan -> scatter)
//           (3) sample in sorted order (gathers hit L2), scatter-store to out[n]

#define CDIM 32
#define SGRID 32
#define NCELL (SGRID * SGRID * SGRID)

// ---- transpose [32, HW] -> [HW, 32], LDS-tiled, 64 positions per block ----
__global__ void transpose_plane(const float* __restrict__ in,
                                float* __restrict__ out, int HW) {
    __shared__ float lds[64][33];
    int p0  = blockIdx.x * 64;
    int tid = threadIdx.x;         // 256 threads
    int pi  = tid & 63;
    int cg  = tid >> 6;
#pragma unroll
    for (int i = 0; i < 8; ++i) {
        int c = cg * 8 + i;
        int p = p0 + pi;
        float v = (p < HW) ? in[(size_t)c * HW + p] : 0.0f;
        lds[pi][c] = v;
    }
    __syncthreads();
    int c2 = tid & 31;
    int pj = tid >> 5;
#pragma unroll
    for (int i = 0; i < 8; ++i) {
        int p = pj + i * 8;
        if (p0 + p < HW)
            out[(size_t)(p0 + p) * CDIM + c2] = lds[p][c2];
    }
}

__device__ __forceinline__ int cell_of(float x, float y, float z) {
    int cx = (int)((x + 4.0f) * 4.0f);  // 8 world units -> 32 cells
    int cy = (int)((y + 4.0f) * 4.0f);
    int cz = (int)((z + 4.0f) * 4.0f);
    cx = min(SGRID - 1, max(0, cx));
    cy = min(SGRID - 1, max(0, cy));
    cz = min(SGRID - 1, max(0, cz));
    return (cx * SGRID + cy) * SGRID + cz;
}

__global__ void hist_kernel(const float* __restrict__ xyz,
                            int* __restrict__ cells, int n) {
    int i = blockIdx.x * blockDim.x + threadIdx.x;
    if (i >= n) return;
    float x = xyz[3 * (size_t)i + 0];
    float y = xyz[3 * (size_t)i + 1];
    float z = xyz[3 * (size_t)i + 2];
    atomicAdd(&cells[cell_of(x, y, z)], 1);
}

// in-place exclusive scan of cells[NCELL]; 1 block x 1024 threads x 32 each
__global__ void scan_cells(int* __restrict__ cells) {
    __shared__ int lds[1024];
    int t = threadIdx.x;
    int base = t * 32;
    int s = 0;
#pragma unroll
    for (int i = 0; i < 32; ++i) s += cells[base + i];
    lds[t] = s;
    __syncthreads();
    for (int off = 1; off < 1024; off <<= 1) {
        int v = 0;
        if (t >= off) v = lds[t - off];
        __syncthreads();
        if (t >= off) lds[t] += v;
        __syncthreads();
    }
    int prefix = (t == 0) ? 0 : lds[t - 1];
#pragma unroll
    for (int i = 0; i < 32; ++i) {
        int j = base + i;
        int c = cells[j];
        cells[j] = prefix;
        prefix += c;
    }
}

// scatter: sortedg[pos] = {gx, gy, gz, bits(orig_index)}
__global__ void scatter_kernel(const float* __restrict__ xyz,
                               int* __restrict__ offs,
                               float4* __restrict__ sortedg, int n) {
    int i = blockIdx.x * blockDim.x + threadIdx.x;
    if (i >= n) return;
    float x = xyz[3 * (size_t)i + 0];
    float y = xyz[3 * (size_t)i + 1];
    float z = xyz[3 * (size_t)i + 2];
    int pos = atomicAdd(&offs[cell_of(x, y, z)], 1);
    float4 v;
    v.x = (x + 4.0f) * 0.25f - 1.0f;
    v.y = (y + 4.0f) * 0.25f - 1.0f;
    v.z = (z + 4.0f) * 0.25f - 1.0f;
    v.w = __int_as_float(i);
    sortedg[pos] = v;
}

// ---- bilinear fetch of 4 channels from channel-last [R,R,32] plane ----
__device__ __forceinline__ float4 bilerp4(const float* __restrict__ base,
                                          int R, float u, float v, int c4) {
    float s = 0.5f * (float)(R - 1);
    float x = (u + 1.0f) * s;
    float y = (v + 1.0f) * s;
    float rm1 = (float)(R - 1);
    x = fminf(fmaxf(x, 0.0f), rm1);
    y = fminf(fmaxf(y, 0.0f), rm1);
    float x0f = floorf(x), y0f = floorf(y);
    int x0 = (int)x0f, y0 = (int)y0f;
    int x1 = min(x0 + 1, R - 1);
    int y1 = min(y0 + 1, R - 1);
    float wx = x - x0f, wy = y - y0f;

    const float* r0 = base + ((size_t)y0 * R) * CDIM + c4;
    const float* r1 = base + ((size_t)y1 * R) * CDIM + c4;
    float4 a = *(const float4*)(r0 + (size_t)x0 * CDIM);
    float4 b = *(const float4*)(r0 + (size_t)x1 * CDIM);
    float4 c = *(const float4*)(r1 + (size_t)x0 * CDIM);
    float4 d = *(const float4*)(r1 + (size_t)x1 * CDIM);

    float w00 = (1.0f - wx) * (1.0f - wy);
    float w01 = wx * (1.0f - wy);
    float w10 = (1.0f - wx) * wy;
    float w11 = wx * wy;
    float4 r;
    r.x = a.x * w00 + b.x * w01 + c.x * w10 + d.x * w11;
    r.y = a.y * w00 + b.y * w01 + c.y * w10 + d.y * w11;
    r.z = a.z * w00 + b.z * w01 + c.z * w10 + d.z * w11;
    r.w = a.w * w00 + b.w * w01 + c.w * w10 + d.w * w11;
    return r;
}

// ---- sampler over sorted order: 16 threads/point, XCD-swizzled blocks ----
__global__ void triplane_sample(const float4* __restrict__ sortedg,
                                const float* __restrict__ planes,
                                float* __restrict__ out, int n_pts) {
    // bijective XCD swizzle (m204): each XCD gets a contiguous chunk
    int nwg  = gridDim.x;
    int orig = blockIdx.x;
    int xcd = orig & 7, local = orig >> 3;
    int q = nwg >> 3, r = nwg & 7;
    int wg = (xcd < r ? xcd * (q + 1) : r * (q + 1) + (xcd - r) * q) + local;

    int tid = wg * 256 + (int)threadIdx.x;
    int i = tid >> 4;
    if (i >= n_pts) return;
    int l     = tid & 15;
    int level = l >> 3;
    int c4    = (l & 7) * 4;

    float4 g = sortedg[i];
    int n_orig = __float_as_int(g.w);

    const size_t CSZ = (size_t)100 * 100 * CDIM;
    const size_t FSZ = (size_t)400 * 400 * CDIM;
    const float* base;
    int R;
    size_t psz;
    if (level == 0) { base = planes;           R = 100; psz = CSZ; }
    else            { base = planes + 3 * CSZ; R = 400; psz = FSZ; }

    float4 fxy = bilerp4(base,           R, g.x, g.y, c4);
    float4 fxz = bilerp4(base + psz,     R, g.x, g.z, c4);
    float4 fyz = bilerp4(base + 2 * psz, R, g.y, g.z, c4);

    float4 o;
    o.x = fxy.x + fxz.x + fyz.x;
    o.y = fxy.y + fxz.y + fyz.y;
    o.z = fxy.z + fxz.z + fyz.z;
    o.w = fxy.w + fxz.w + fyz.w;

    *(float4*)(out + (size_t)n_orig * 64 + level * 32 + c4) = o;
}

extern "C" void kernel_launch(void* const* d_in, const int* in_sizes, int n_in,
                              void* d_out, int out_size, void* d_ws, size_t ws_size,
                              hipStream_t stream) {
    const float* xyz = (const float*)d_in[0];
    int n = in_sizes[0] / 3;

    const int CHW = 100 * 100;
    const int FHW = 400 * 400;
    const size_t CSZ = (size_t)CHW * CDIM;
    const size_t FSZ = (size_t)FHW * CDIM;
    const size_t PLANES = 3 * CSZ + 3 * FSZ;  // floats

    float*  ws      = (float*)d_ws;
    int*    cells   = (int*)(ws + PLANES);                                   // NCELL ints
    float4* sortedg = (float4*)((char*)d_ws + PLANES * 4 + (size_t)NCELL * 4);

    dim3 blk(256);
    transpose_plane<<<(CHW + 63) / 64, blk, 0, stream>>>((const float*)d_in[1], ws, CHW);
    transpose_plane<<<(CHW + 63) / 64, blk, 0, stream>>>((const float*)d_in[2], ws + CSZ, CHW);
    transpose_plane<<<(CHW + 63) / 64, blk, 0, stream>>>((const float*)d_in[3], ws + 2 * CSZ, CHW);
    transpose_plane<<<(FHW + 63) / 64, blk, 0, stream>>>((const float*)d_in[4], ws + 3 * CSZ, FHW);
    transpose_plane<<<(FHW + 63) / 64, blk, 0, stream>>>((const float*)d_in[5], ws + 3 * CSZ + FSZ, FHW);
    transpose_plane<<<(FHW + 63) / 64, blk, 0, stream>>>((const float*)d_in[6], ws + 3 * CSZ + 2 * FSZ, FHW);

    hipMemsetAsync(cells, 0, (size_t)NCELL * 4, stream);
    hist_kernel<<<(n + 255) / 256, blk, 0, stream>>>(xyz, cells, n);
    scan_cells<<<1, 1024, 0, stream>>>(cells);
    scatter_kernel<<<(n + 255) / 256, blk, 0, stream>>>(xyz, cells, sortedg, n);

    long long total_threads = (long long)n * 16;
    int nblk = (int)((total_threads + 255) / 256);
    triplane_sample<<<nblk, blk, 0, stream>>>(sortedg, ws, (float*)d_out, n);
}

// Round 4
// 285.842 us; speedup vs baseline: 1.4938x; 1.1307x over previous
//
#include <hip/hip_runtime.h>

// TriPlane sampling with Morton-order spatial counting-sort.
// (1) one fused kernel transposes 6 planes [C,H,W] -> [H,W,C] into d_ws
// (2) counting-sort points into 32^3 Morton-ordered cells
// (3) sample in sorted order (3D-local -> L2-hit gathers), scatter-store out

#define CDIM 32
#define SGRID 32
#define NCELL (SGRID * SGRID * SGRID)
#define CHW 10000
#define FHW 160000
#define CBLK 157          // ceil(10000/64)
#define FBLK 2500         // 160000/64

struct PlanePtrs { const float* p[6]; };

// ---- fused transpose: [32,HW] -> [HW,32] for all 6 planes ----
__global__ void transpose_all(PlanePtrs in, float* __restrict__ out) {
    __shared__ float lds[64][33];
    const size_t CSZ = (size_t)CHW * CDIM;
    const size_t FSZ = (size_t)FHW * CDIM;

    int b = blockIdx.x;
    const float* src;
    float* dst;
    int HW, local;
    if (b < 3 * CBLK) {
        int plane = b / CBLK; local = b - plane * CBLK;
        src = in.p[plane]; dst = out + (size_t)plane * CSZ; HW = CHW;
    } else {
        b -= 3 * CBLK;
        int plane = b / FBLK; local = b - plane * FBLK;
        src = in.p[3 + plane]; dst = out + 3 * CSZ + (size_t)plane * FSZ; HW = FHW;
    }

    int p0  = local * 64;
    int tid = threadIdx.x;
    int pi  = tid & 63;
    int cg  = tid >> 6;
#pragma unroll
    for (int i = 0; i < 8; ++i) {
        int c = cg * 8 + i;
        int p = p0 + pi;
        float v = (p < HW) ? src[(size_t)c * HW + p] : 0.0f;
        lds[pi][c] = v;
    }
    __syncthreads();
    int c2 = tid & 31;
    int pj = tid >> 5;
#pragma unroll
    for (int i = 0; i < 8; ++i) {
        int p = pj + i * 8;
        if (p0 + p < HW)
            dst[(size_t)(p0 + p) * CDIM + c2] = lds[p][c2];
    }
}

// ---- Morton cell index: 3D locality along the sorted order ----
__device__ __forceinline__ int spread3(int v) {  // 5-bit -> every 3rd bit
    v = (v | (v << 16)) & 0x030000FF;
    v = (v | (v << 8))  & 0x0300F00F;
    v = (v | (v << 4))  & 0x030C30C3;
    v = (v | (v << 2))  & 0x09249249;
    return v;
}

__device__ __forceinline__ int cell_of(float x, float y, float z) {
    int cx = (int)((x + 4.0f) * 4.0f);
    int cy = (int)((y + 4.0f) * 4.0f);
    int cz = (int)((z + 4.0f) * 4.0f);
    cx = min(SGRID - 1, max(0, cx));
    cy = min(SGRID - 1, max(0, cy));
    cz = min(SGRID - 1, max(0, cz));
    return spread3(cx) | (spread3(cy) << 1) | (spread3(cz) << 2);
}

__global__ void hist_kernel(const float* __restrict__ xyz,
                            int* __restrict__ cells, int n) {
    int i = blockIdx.x * blockDim.x + threadIdx.x;
    if (i >= n) return;
    float x = xyz[3 * (size_t)i + 0];
    float y = xyz[3 * (size_t)i + 1];
    float z = xyz[3 * (size_t)i + 2];
    atomicAdd(&cells[cell_of(x, y, z)], 1);
}

// in-place exclusive scan of cells[NCELL]; 1 block x 1024 thr x 32 cells (int4)
__global__ void scan_cells(int* __restrict__ cells) {
    __shared__ int lds[1024];
    int t = threadIdx.x;
    int4* c4p = (int4*)cells;
    int4 v[8];
    int s = 0;
#pragma unroll
    for (int i = 0; i < 8; ++i) {
        v[i] = c4p[t * 8 + i];
        s += v[i].x + v[i].y + v[i].z + v[i].w;
    }
    lds[t] = s;
    __syncthreads();
    for (int off = 1; off < 1024; off <<= 1) {
        int u = 0;
        if (t >= off) u = lds[t - off];
        __syncthreads();
        if (t >= off) lds[t] += u;
        __syncthreads();
    }
    int prefix = (t == 0) ? 0 : lds[t - 1];
#pragma unroll
    for (int i = 0; i < 8; ++i) {
        int a = v[i].x, b = v[i].y, c = v[i].z, d = v[i].w;
        v[i].x = prefix;
        v[i].y = prefix + a;
        v[i].z = prefix + a + b;
        v[i].w = prefix + a + b + c;
        prefix += a + b + c + d;
        c4p[t * 8 + i] = v[i];
    }
}

__global__ void scatter_kernel(const float* __restrict__ xyz,
                               int* __restrict__ offs,
                               float4* __restrict__ sortedg, int n) {
    int i = blockIdx.x * blockDim.x + threadIdx.x;
    if (i >= n) return;
    float x = xyz[3 * (size_t)i + 0];
    float y = xyz[3 * (size_t)i + 1];
    float z = xyz[3 * (size_t)i + 2];
    int pos = atomicAdd(&offs[cell_of(x, y, z)], 1);
    float4 v;
    v.x = (x + 4.0f) * 0.25f - 1.0f;
    v.y = (y + 4.0f) * 0.25f - 1.0f;
    v.z = (z + 4.0f) * 0.25f - 1.0f;
    v.w = __int_as_float(i);
    sortedg[pos] = v;
}

// ---- bilinear fetch of 4 channels from channel-last [R,R,32] plane ----
__device__ __forceinline__ float4 bilerp4(const float* __restrict__ base,
                                          int R, float u, float v, int c4) {
    float s = 0.5f * (float)(R - 1);
    float x = (u + 1.0f) * s;
    float y = (v + 1.0f) * s;
    float rm1 = (float)(R - 1);
    x = fminf(fmaxf(x, 0.0f), rm1);
    y = fminf(fmaxf(y, 0.0f), rm1);
    float x0f = floorf(x), y0f = floorf(y);
    int x0 = (int)x0f, y0 = (int)y0f;
    int x1 = min(x0 + 1, R - 1);
    int y1 = min(y0 + 1, R - 1);
    float wx = x - x0f, wy = y - y0f;

    const float* r0 = base + ((size_t)y0 * R) * CDIM + c4;
    const float* r1 = base + ((size_t)y1 * R) * CDIM + c4;
    float4 a = *(const float4*)(r0 + (size_t)x0 * CDIM);
    float4 b = *(const float4*)(r0 + (size_t)x1 * CDIM);
    float4 c = *(const float4*)(r1 + (size_t)x0 * CDIM);
    float4 d = *(const float4*)(r1 + (size_t)x1 * CDIM);

    float w00 = (1.0f - wx) * (1.0f - wy);
    float w01 = wx * (1.0f - wy);
    float w10 = (1.0f - wx) * wy;
    float w11 = wx * wy;
    float4 r;
    r.x = a.x * w00 + b.x * w01 + c.x * w10 + d.x * w11;
    r.y = a.y * w00 + b.y * w01 + c.y * w10 + d.y * w11;
    r.z = a.z * w00 + b.z * w01 + c.z * w10 + d.z * w11;
    r.w = a.w * w00 + b.w * w01 + c.w * w10 + d.w * w11;
    return r;
}

// ---- sampler over sorted order: 16 threads/point, XCD-swizzled blocks ----
__global__ void triplane_sample(const float4* __restrict__ sortedg,
                                const float* __restrict__ planes,
                                float* __restrict__ out, int n_pts) {
    int nwg  = gridDim.x;
    int orig = blockIdx.x;
    int xcd = orig & 7, local = orig >> 3;
    int q = nwg >> 3, r = nwg & 7;
    int wg = (xcd < r ? xcd * (q + 1) : r * (q + 1) + (xcd - r) * q) + local;

    int tid = wg * 256 + (int)threadIdx.x;
    int i = tid >> 4;
    if (i >= n_pts) return;
    int l     = tid & 15;
    int level = l >> 3;
    int c4    = (l & 7) * 4;

    float4 g = sortedg[i];
    int n_orig = __float_as_int(g.w);

    const size_t CSZ = (size_t)CHW * CDIM;
    const size_t FSZ = (size_t)FHW * CDIM;
    const float* base;
    int R;
    size_t psz;
    if (level == 0) { base = planes;           R = 100; psz = CSZ; }
    else            { base = planes + 3 * CSZ; R = 400; psz = FSZ; }

    float4 fxy = bilerp4(base,           R, g.x, g.y, c4);
    float4 fxz = bilerp4(base + psz,     R, g.x, g.z, c4);
    float4 fyz = bilerp4(base + 2 * psz, R, g.y, g.z, c4);

    float4 o;
    o.x = fxy.x + fxz.x + fyz.x;
    o.y = fxy.y + fxz.y + fyz.y;
    o.z = fxy.z + fxz.z + fyz.z;
    o.w = fxy.w + fxz.w + fyz.w;

    *(float4*)(out + (size_t)n_orig * 64 + level * 32 + c4) = o;
}

extern "C" void kernel_launch(void* const* d_in, const int* in_sizes, int n_in,
                              void* d_out, int out_size, void* d_ws, size_t ws_size,
                              hipStream_t stream) {
    const float* xyz = (const float*)d_in[0];
    int n = in_sizes[0] / 3;

    const size_t CSZ = (size_t)CHW * CDIM;
    const size_t FSZ = (size_t)FHW * CDIM;
    const size_t PLANES = 3 * CSZ + 3 * FSZ;  // floats

    float*  ws      = (float*)d_ws;
    int*    cells   = (int*)(ws + PLANES);
    float4* sortedg = (float4*)((char*)d_ws + PLANES * 4 + (size_t)NCELL * 4);

    dim3 blk(256);
    PlanePtrs pp;
    for (int k = 0; k < 6; ++k) pp.p[k] = (const float*)d_in[1 + k];
    transpose_all<<<3 * CBLK + 3 * FBLK, blk, 0, stream>>>(pp, ws);

    hipMemsetAsync(cells, 0, (size_t)NCELL * 4, stream);
    hist_kernel<<<(n + 255) / 256, blk, 0, stream>>>(xyz, cells, n);
    scan_cells<<<1, 1024, 0, stream>>>(cells);
    scatter_kernel<<<(n + 255) / 256, blk, 0, stream>>>(xyz, cells, sortedg, n);

    long long total_threads = (long long)n * 16;
    int nblk = (int)((total_threads + 255) / 256);
    triplane_sample<<<nblk, blk, 0, stream>>>(sortedg, ws, (float*)d_out, n);
}